// Round 10
// baseline (294.820 us; speedup 1.0000x reference)
//
#include <hip/hip_runtime.h>
#include <math.h>

#define NV 100000
#define NK 64
#define NF 16
#define EPS_W 1e-4f
#define GRID_F 3125          // 3125 blocks * 4 waves * 8 iter = 100000 vertices

typedef __attribute__((ext_vector_type(8))) short bf16x8;
typedef __attribute__((ext_vector_type(4))) float f32x4;

__device__ __forceinline__ unsigned short bfu(float x) {
    return __builtin_bit_cast(unsigned short, (__bf16)x);   // HW RNE cvt
}
__device__ __forceinline__ unsigned int pk2(float lo, float hi) {
    return (unsigned int)bfu(lo) | ((unsigned int)bfu(hi) << 16);
}
__device__ __forceinline__ float eluf(float x) {
    return x > 0.f ? x : __expf(x) - 1.f;
}

// hbuf fragment helpers (r2-r9 verified; XOR swizzle keeps conflicts <=2-way)
__device__ __forceinline__ bf16x8 rdfrag(const short* hb, int c, int g, int kc) {
    int boff = ((kc << 6) + (g << 4)) ^ ((c & 7) << 4);
    return *(const bf16x8*)(hb + c * 64 + (boff >> 1));
}
__device__ __forceinline__ void wrH(short* hb, int c, int g, int t,
                                    unsigned int p01, unsigned int p23) {
    int boff = ((t << 5) + (g << 3)) ^ ((c & 7) << 4);
    uint2 val; val.x = p01; val.y = p23;
    *(uint2*)(hb + c * 64 + (boff >> 1)) = val;
}
__device__ __forceinline__ bf16x8 rdW(const short* sw, int c, int g, int t, int kc) {
    int byte = (t << 11) + (c << 7) + (kc << 6) + (g << 4);
    byte ^= (c & 7) << 4;
    return *(const bf16x8*)((const char*)sw + byte);
}

// ---------------------------------------------------------------------------
// fused6: one wave = one vertex per iteration.
//   Phase 1 (cov): lane (c,g) accumulates feature-c stats over k in
//   [16g,16g+16) from LDS-staged (ew,idx); shfl_xor(16,32) allreduce gives
//   every lane the full cov -> layer-0 B fragment built in registers.
//   Phase 2 (mlp): r9-verified MFMA chain, biases in C-init, W1/W2 in
//   swizzled LDS, full-sector float4 epilogue via LDS staging.
// D layout: col=lane&15, row=4*(lane>>4)+reg.  A/B: row/col=lane&15, k=8*(lane>>4)+i.
// ---------------------------------------------------------------------------
__launch_bounds__(256, 4)
__global__ void fused6_kernel(const float* __restrict__ coords,
                              const float* __restrict__ distsq,
                              const float* __restrict__ feats,
                              const int*   __restrict__ nidx,
                              const float* __restrict__ W0, const float* __restrict__ b0,
                              const float* __restrict__ W1, const float* __restrict__ b1,
                              const float* __restrict__ W2, const float* __restrict__ b2,
                              const float* __restrict__ W3, const float* __restrict__ b3,
                              float* __restrict__ out)
{
    __shared__ __align__(16) short sW1[4096];          // 8 KB swizzled W1^T
    __shared__ __align__(16) short sW2[4096];          // 8 KB swizzled W2^T
    __shared__ __align__(16) short hbuf[4][1024];      // 8 KB activation bounce
    __shared__ float sEW[4][64];                       // 1 KB per-wave ew
    __shared__ int   sIX[4][64];                       // 1 KB per-wave idx

    const int tid  = threadIdx.x;
    const int wid  = tid >> 6;
    const int lane = tid & 63;
    const int c    = lane & 15;        // feature / MFMA col / A-row
    const int g    = lane >> 4;        // k-group / cov k-quarter

    union U8 { short s[8]; bf16x8 v; };

    // ---- stage W1,W2 into swizzled LDS ----
    #pragma unroll
    for (int r = 0; r < 2; ++r) {
        int t = tid + r * 256;          // task: j = t&63, k-oct o = t>>6
        int j = t & 63, o = t >> 6;
        U8 u1, u2;
        #pragma unroll
        for (int i = 0; i < 8; ++i) {
            u1.s[i] = (short)bfu(W1[(8 * o + i) * 64 + j]);
            u2.s[i] = (short)bfu(W2[(8 * o + i) * 64 + j]);
        }
        int byte = ((j << 7) + (o << 4)) ^ ((j & 7) << 4);
        *(bf16x8*)((char*)sW1 + byte) = u1.v;
        *(bf16x8*)((char*)sW2 + byte) = u2.v;
    }
    __syncthreads();

    // ---- W0 / W3 fragments + biases in VGPRs ----
    bf16x8 w0f[4], w3f[2];
    #pragma unroll
    for (int t = 0; t < 4; ++t) {
        U8 u;
        #pragma unroll
        for (int i = 0; i < 8; ++i) {
            int k = 8 * g + i;
            float val = 0.f;
            if (k < 9)       val = W0[k * 64 + 16 * t + c];
            else if (k == 9) val = b0[16 * t + c];       // bias via dim-9 = 1.0
            u.s[i] = (short)bfu(val);
        }
        w0f[t] = u.v;
    }
    #pragma unroll
    for (int kc = 0; kc < 2; ++kc) {
        U8 u;
        #pragma unroll
        for (int i = 0; i < 8; ++i) {
            int k = 32 * kc + 8 * g + i;
            u.s[i] = (short)bfu(c < 9 ? W3[k * 9 + c] : 0.f);
        }
        w3f[kc] = u.v;
    }
    float b1v[16], b2v[16], b3v[4];
    #pragma unroll
    for (int t = 0; t < 4; ++t)
        #pragma unroll
        for (int r = 0; r < 4; ++r) {
            b1v[4 * t + r] = b1[16 * t + 4 * g + r];
            b2v[4 * t + r] = b2[16 * t + 4 * g + r];
        }
    #pragma unroll
    for (int r = 0; r < 4; ++r)
        b3v[r] = (4 * g + r < 9) ? b3[4 * g + r] : 0.f;

    short* hb = &hbuf[wid][0];
    float* fOut = (float*)hb;      // hbuf is dead during the epilogue

    const int stride = gridDim.x * 4;
    float* ob = out + (size_t)(blockIdx.x * 4 + wid) * 144;
    const size_t ostep = (size_t)stride * 144;

    for (int v = blockIdx.x * 4 + wid; v < NV; v += stride) {
        // ---- stage ew/idx: one coalesced element per lane ----
        {
            float d  = distsq[(size_t)v * NK + lane];
            int   ix = nidx[(size_t)v * NK + lane];
            sEW[wid][lane] = __expf(-10.f * d);
            sIX[wid][lane] = ix;
        }
        __asm__ volatile("s_waitcnt lgkmcnt(0)" ::: "memory");

        // ---- cov: lane (c,g) sums k = 16g .. 16g+15 for feature c ----
        float s = 0.f, m0 = 0.f, m1 = 0.f, m2 = 0.f;
        float q00 = 0.f, q01 = 0.f, q02 = 0.f, q11 = 0.f, q12 = 0.f, q22 = 0.f;
        #pragma unroll 4
        for (int i = 0; i < 16; ++i) {
            int   k   = 16 * g + i;
            int   idx = sIX[wid][k];
            float ew  = sEW[wid][k];
            float ft  = feats[(size_t)idx * NF + c];   // 16 c-lanes share one line
            float x = coords[(size_t)idx * 3 + 0];
            float y = coords[(size_t)idx * 3 + 1];
            float z = coords[(size_t)idx * 3 + 2];
            float w = ft * ew;
            s += w;
            m0 = fmaf(w, x, m0); m1 = fmaf(w, y, m1); m2 = fmaf(w, z, m2);
            float wx = w * x, wy = w * y, wz = w * z;
            q00 = fmaf(wx, x, q00); q01 = fmaf(wx, y, q01); q02 = fmaf(wx, z, q02);
            q11 = fmaf(wy, y, q11); q12 = fmaf(wy, z, q12);
            q22 = fmaf(wz, z, q22);
        }
        // allreduce over the 4 g-lanes (lanes c, c+16, c+32, c+48)
        #define RED2(a) { a += __shfl_xor(a, 16); a += __shfl_xor(a, 32); }
        RED2(s)  RED2(m0) RED2(m1) RED2(m2)
        RED2(q00) RED2(q01) RED2(q02) RED2(q11) RED2(q12) RED2(q22)
        #undef RED2

        float inv = 1.f / (s + EPS_W);
        float mu0 = m0 * inv, mu1 = m1 * inv, mu2 = m2 * inv;
        float c00 = fmaf(-mu0, mu0, q00 * inv);
        float c01 = fmaf(-mu0, mu1, q01 * inv);
        float c02 = fmaf(-mu0, mu2, q02 * inv);
        float c11 = fmaf(-mu1, mu1, q11 * inv);
        float c12 = fmaf(-mu1, mu2, q12 * inv);
        float c22 = fmaf(-mu2, mu2, q22 * inv);

        // ---- layer-0 B fragment straight from registers ----
        // row = [c00 c01 c02 | c01 c11 c12 | c02 c12 c22 | 1.0 | 0...]
        bf16x8 bin;
        {
            union { unsigned int u[4]; bf16x8 v; } B;
            if (g == 0) {
                B.u[0] = pk2(c00, c01); B.u[1] = pk2(c02, c01);
                B.u[2] = pk2(c11, c12); B.u[3] = pk2(c02, c12);
            } else if (g == 1) {
                B.u[0] = pk2(c22, 1.0f); B.u[1] = 0u; B.u[2] = 0u; B.u[3] = 0u;
            } else {
                B.u[0] = 0u; B.u[1] = 0u; B.u[2] = 0u; B.u[3] = 0u;
            }
            bin = B.v;
        }

        f32x4 A[4];

        // ---- layer 0 (bias via k=9 slot; C = 0) ----
        #pragma unroll
        for (int t = 0; t < 4; ++t) {
            f32x4 z4 = {0.f, 0.f, 0.f, 0.f};
            A[t] = __builtin_amdgcn_mfma_f32_16x16x32_bf16(w0f[t], bin, z4, 0, 0, 0);
        }
        #pragma unroll
        for (int t = 0; t < 4; ++t)
            wrH(hb, c, g, t, pk2(eluf(A[t][0]), eluf(A[t][1])),
                             pk2(eluf(A[t][2]), eluf(A[t][3])));
        __asm__ volatile("s_waitcnt lgkmcnt(0)" ::: "memory");

        // ---- layer 1 (C = b1) ----
        {
            bf16x8 h0 = rdfrag(hb, c, g, 0), h1 = rdfrag(hb, c, g, 1);
            #pragma unroll
            for (int t = 0; t < 4; ++t) {
                bf16x8 wa = rdW(sW1, c, g, t, 0);
                bf16x8 wb = rdW(sW1, c, g, t, 1);
                f32x4 a = { b1v[4*t+0], b1v[4*t+1], b1v[4*t+2], b1v[4*t+3] };
                a = __builtin_amdgcn_mfma_f32_16x16x32_bf16(wa, h0, a, 0, 0, 0);
                a = __builtin_amdgcn_mfma_f32_16x16x32_bf16(wb, h1, a, 0, 0, 0);
                A[t] = a;
            }
            #pragma unroll
            for (int t = 0; t < 4; ++t)
                wrH(hb, c, g, t, pk2(eluf(A[t][0]), eluf(A[t][1])),
                                 pk2(eluf(A[t][2]), eluf(A[t][3])));
        }
        __asm__ volatile("s_waitcnt lgkmcnt(0)" ::: "memory");

        // ---- layer 2 (C = b2) ----
        {
            bf16x8 h0 = rdfrag(hb, c, g, 0), h1 = rdfrag(hb, c, g, 1);
            #pragma unroll
            for (int t = 0; t < 4; ++t) {
                bf16x8 wa = rdW(sW2, c, g, t, 0);
                bf16x8 wb = rdW(sW2, c, g, t, 1);
                f32x4 a = { b2v[4*t+0], b2v[4*t+1], b2v[4*t+2], b2v[4*t+3] };
                a = __builtin_amdgcn_mfma_f32_16x16x32_bf16(wa, h0, a, 0, 0, 0);
                a = __builtin_amdgcn_mfma_f32_16x16x32_bf16(wb, h1, a, 0, 0, 0);
                A[t] = a;
            }
            #pragma unroll
            for (int t = 0; t < 4; ++t)
                wrH(hb, c, g, t, pk2(eluf(A[t][0]), eluf(A[t][1])),
                                 pk2(eluf(A[t][2]), eluf(A[t][3])));
        }
        __asm__ volatile("s_waitcnt lgkmcnt(0)" ::: "memory");

        // ---- layer 3: 64 -> 9 (C = b3), stage to LDS ----
        {
            bf16x8 h0 = rdfrag(hb, c, g, 0), h1 = rdfrag(hb, c, g, 1);
            f32x4 a = { b3v[0], b3v[1], b3v[2], b3v[3] };
            a = __builtin_amdgcn_mfma_f32_16x16x32_bf16(w3f[0], h0, a, 0, 0, 0);
            a = __builtin_amdgcn_mfma_f32_16x16x32_bf16(w3f[1], h1, a, 0, 0, 0);
            if (g < 2) {
                fOut[c * 9 + 4 * g + 0] = eluf(a[0]);
                fOut[c * 9 + 4 * g + 1] = eluf(a[1]);
                fOut[c * 9 + 4 * g + 2] = eluf(a[2]);
                fOut[c * 9 + 4 * g + 3] = eluf(a[3]);
            } else if (g == 2) {
                fOut[c * 9 + 8] = eluf(a[0]);
            }
        }
        __asm__ volatile("s_waitcnt lgkmcnt(0)" ::: "memory");

        // ---- full-sector store: 36 lanes x contiguous float4 = 576B ----
        if (lane < 36) {
            float4 val = *(const float4*)(fOut + lane * 4);
            *(float4*)(ob + lane * 4) = val;
        }
        __asm__ volatile("s_waitcnt lgkmcnt(0)" ::: "memory");  // fOut reads done before next wrH

        ob += ostep;
    }
}

extern "C" void kernel_launch(void* const* d_in, const int* in_sizes, int n_in,
                              void* d_out, int out_size, void* d_ws, size_t ws_size,
                              hipStream_t stream) {
    (void)in_sizes; (void)n_in; (void)out_size; (void)d_ws; (void)ws_size;
    const float* coords = (const float*)d_in[0];
    const float* distsq = (const float*)d_in[1];
    const float* feats  = (const float*)d_in[2];
    const int*   nidx   = (const int*)d_in[3];
    const float* W0 = (const float*)d_in[4];
    const float* b0 = (const float*)d_in[5];
    const float* W1 = (const float*)d_in[6];
    const float* b1 = (const float*)d_in[7];
    const float* W2 = (const float*)d_in[8];
    const float* b2 = (const float*)d_in[9];
    const float* W3 = (const float*)d_in[10];
    const float* b3 = (const float*)d_in[11];
    float* out = (float*)d_out;

    hipLaunchKernelGGL(fused6_kernel, dim3(GRID_F), dim3(256), 0, stream,
                       coords, distsq, feats, nidx,
                       W0, b0, W1, b1, W2, b2, W3, b3, out);
}

// Round 11
// 214.832 us; speedup vs baseline: 1.3723x; 1.3723x over previous
//
#include <hip/hip_runtime.h>
#include <math.h>

#define NV 100000
#define NK 64
#define NF 16
#define EPS_W 1e-4f
#define WS_NEED ((size_t)NV * 16 * 32)   // 51.2 MB bf16 rows
#define GRID_MLP 3125                    // 12500 waves * 8 = 100000 vertices

typedef __attribute__((ext_vector_type(8))) short bf16x8;
typedef __attribute__((ext_vector_type(4))) float f32x4;

__device__ __forceinline__ unsigned short bfu(float x) {
    return __builtin_bit_cast(unsigned short, (__bf16)x);   // HW RNE cvt
}
__device__ __forceinline__ unsigned int pk2(float lo, float hi) {
    return (unsigned int)bfu(lo) | ((unsigned int)bfu(hi) << 16);
}
__device__ __forceinline__ float eluf(float x) {
    return x > 0.f ? x : __expf(x) - 1.f;
}

// ---------------------------------------------------------------------------
// Kernel A (cov3): split-K covariance. Wave = 2 vertices x 16 f x 2 k-halves
// (32 iters/thread, 50K waves for latency hiding); shfl_xor(16) reduce.
// Output rows [v*16+f][16]: dims 0-8 cov, dim 9 = 1.0 (bias slot), rest 0.
// ---------------------------------------------------------------------------
__launch_bounds__(256)
__global__ void cov3_kernel(const float* __restrict__ coords,
                            const float* __restrict__ distsq,
                            const float* __restrict__ feats,
                            const int*   __restrict__ nidx,
                            unsigned char* __restrict__ ws)
{
    __shared__ float sEW[8][64];
    __shared__ int   sIX[8][64];
    const int tid = threadIdx.x;
    const int vb  = blockIdx.x * 8;

    // stage: 8 vertices x 64 k = 512 tasks, 2/thread, coalesced
    #pragma unroll
    for (int r = 0; r < 2; ++r) {
        int t  = tid + r * 256;
        int gv = t >> 6, k = t & 63;
        float d  = distsq[(size_t)(vb + gv) * NK + k];
        int   ix = nidx [(size_t)(vb + gv) * NK + k];
        sEW[gv][k] = __expf(-10.f * d);
        sIX[gv][k] = ix;
    }
    __syncthreads();

    const int lane = tid & 63;
    const int wid  = tid >> 6;
    const int f    = lane & 15;
    const int kh   = (lane >> 4) & 1;       // k-half
    const int g2   = lane >> 5;             // vertex-in-wave
    const int gv   = wid * 2 + g2;
    const int v    = vb + gv;

    float s=0.f, m0=0.f,m1=0.f,m2=0.f;
    float q00=0.f,q01=0.f,q02=0.f,q11=0.f,q12=0.f,q22=0.f;

    #pragma unroll 8
    for (int i = 0; i < 32; ++i) {
        int   k   = kh * 32 + i;
        int   idx = sIX[gv][k];
        float ew  = sEW[gv][k];
        float w   = feats[(size_t)idx * NF + f] * ew;   // 16 f-lanes share line
        float x = coords[(size_t)idx*3+0];
        float y = coords[(size_t)idx*3+1];
        float z = coords[(size_t)idx*3+2];
        s += w;
        m0 = fmaf(w,x,m0); m1 = fmaf(w,y,m1); m2 = fmaf(w,z,m2);
        float wx=w*x, wy=w*y, wz=w*z;
        q00=fmaf(wx,x,q00); q01=fmaf(wx,y,q01); q02=fmaf(wx,z,q02);
        q11=fmaf(wy,y,q11); q12=fmaf(wy,z,q12); q22=fmaf(wz,z,q22);
    }
    // combine the two k-halves (partner = lane ^ 16)
    s   += __shfl_xor(s,   16);
    m0  += __shfl_xor(m0,  16);
    m1  += __shfl_xor(m1,  16);
    m2  += __shfl_xor(m2,  16);
    q00 += __shfl_xor(q00, 16);
    q01 += __shfl_xor(q01, 16);
    q02 += __shfl_xor(q02, 16);
    q11 += __shfl_xor(q11, 16);
    q12 += __shfl_xor(q12, 16);
    q22 += __shfl_xor(q22, 16);

    if (kh == 0) {
        float inv = 1.f / (s + EPS_W);
        float mu0=m0*inv, mu1=m1*inv, mu2=m2*inv;
        float c00=fmaf(-mu0,mu0,q00*inv);
        float c01=fmaf(-mu0,mu1,q01*inv);
        float c02=fmaf(-mu0,mu2,q02*inv);
        float c11=fmaf(-mu1,mu1,q11*inv);
        float c12=fmaf(-mu1,mu2,q12*inv);
        float c22=fmaf(-mu2,mu2,q22*inv);

        uint4 lo, hi;
        lo.x = pk2(c00, c01);
        lo.y = pk2(c02, c01);
        lo.z = pk2(c11, c12);
        lo.w = pk2(c02, c12);
        hi.x = pk2(c22, 1.0f);
        hi.y = 0u; hi.z = 0u; hi.w = 0u;

        uint4* dst = (uint4*)(ws + ((size_t)v * 16 + f) * 32);
        dst[0] = lo;
        dst[1] = hi;
    }
}

// ---------------------------------------------------------------------------
// Kernel B (mlp6): MFMA MLP with IN-REGISTER layer transitions.
// D layout: col=lane&15, row=16t+4(lane>>4)+reg.  B: col=lane&15, k=32kc+8g+i.
// Transition (verified bijection): B(c,g,kc)[i] = D(tile 2kc+(g>>1),
//   src lane 2(g&1)+(i>>2), reg i&3)  -> 16 shfl + 8 selects, no LDS bounce.
// ---------------------------------------------------------------------------
__device__ __forceinline__ bf16x8 rdW(const short* sw, int c, int g, int t, int kc) {
    int byte = (t << 11) + (c << 7) + (kc << 6) + (g << 4);
    byte ^= (c & 7) << 4;
    return *(const bf16x8*)((const char*)sw + byte);
}

struct B2 { bf16x8 b0, b1; };
__device__ __forceinline__ B2 d2b(const unsigned int pk_[4][2], int c, int g) {
    const int srcA = c + ((g & 1) << 5);    // lane of group 2*(g&1)
    const int srcB = srcA + 16;             // lane of group 2*(g&1)+1
    const bool hi = (g >> 1) != 0;
    union { unsigned int u[4]; bf16x8 v; } U0, U1;
    #pragma unroll
    for (int m = 0; m < 4; ++m) {
        int src = (m & 2) ? srcB : srcA;
        int j   = m & 1;
        unsigned int e0 = (unsigned int)__shfl((int)pk_[0][j], src);
        unsigned int o0 = (unsigned int)__shfl((int)pk_[1][j], src);
        unsigned int e1 = (unsigned int)__shfl((int)pk_[2][j], src);
        unsigned int o1 = (unsigned int)__shfl((int)pk_[3][j], src);
        U0.u[m] = hi ? o0 : e0;
        U1.u[m] = hi ? o1 : e1;
    }
    B2 r; r.b0 = U0.v; r.b1 = U1.v; return r;
}

__launch_bounds__(256, 4)
__global__ void mlp6_kernel(const unsigned char* __restrict__ ws,
                            const float* __restrict__ W0, const float* __restrict__ b0,
                            const float* __restrict__ W1, const float* __restrict__ b1,
                            const float* __restrict__ W2, const float* __restrict__ b2,
                            const float* __restrict__ W3, const float* __restrict__ b3,
                            float* __restrict__ out)
{
    __shared__ __align__(16) short sW1[4096];      // 8 KB swizzled W1^T
    __shared__ __align__(16) short sW2[4096];      // 8 KB swizzled W2^T
    __shared__ __align__(16) float sOut[4][160];   // 2.5 KB epilogue staging

    const int tid  = threadIdx.x;
    const int wid  = tid >> 6;
    const int lane = tid & 63;
    const int c    = lane & 15;
    const int g    = lane >> 4;

    union U8 { short s[8]; bf16x8 v; };

    // ---- stage W1,W2 into swizzled LDS ----
    #pragma unroll
    for (int r = 0; r < 2; ++r) {
        int t = tid + r * 256;          // task: j = t&63, k-oct o = t>>6
        int j = t & 63, o = t >> 6;
        U8 u1, u2;
        #pragma unroll
        for (int i = 0; i < 8; ++i) {
            u1.s[i] = (short)bfu(W1[(8 * o + i) * 64 + j]);
            u2.s[i] = (short)bfu(W2[(8 * o + i) * 64 + j]);
        }
        int byte = ((j << 7) + (o << 4)) ^ ((j & 7) << 4);
        *(bf16x8*)((char*)sW1 + byte) = u1.v;
        *(bf16x8*)((char*)sW2 + byte) = u2.v;
    }
    __syncthreads();

    // ---- W0 / W3 fragments + biases in VGPRs ----
    bf16x8 w0f[4], w3f[2];
    #pragma unroll
    for (int t = 0; t < 4; ++t) {
        U8 u;
        #pragma unroll
        for (int i = 0; i < 8; ++i) {
            int k = 8 * g + i;
            float val = 0.f;
            if (k < 9)       val = W0[k * 64 + 16 * t + c];
            else if (k == 9) val = b0[16 * t + c];       // bias via dim-9 = 1.0
            u.s[i] = (short)bfu(val);
        }
        w0f[t] = u.v;
    }
    #pragma unroll
    for (int kc = 0; kc < 2; ++kc) {
        U8 u;
        #pragma unroll
        for (int i = 0; i < 8; ++i) {
            int k = 32 * kc + 8 * g + i;
            u.s[i] = (short)bfu(c < 9 ? W3[k * 9 + c] : 0.f);
        }
        w3f[kc] = u.v;
    }
    float b1v[16], b2v[16], b3v[4];
    #pragma unroll
    for (int t = 0; t < 4; ++t)
        #pragma unroll
        for (int r = 0; r < 4; ++r) {
            b1v[4 * t + r] = b1[16 * t + 4 * g + r];
            b2v[4 * t + r] = b2[16 * t + 4 * g + r];
        }
    #pragma unroll
    for (int r = 0; r < 4; ++r)
        b3v[r] = (4 * g + r < 9) ? b3[4 * g + r] : 0.f;

    float* fOut = &sOut[wid][0];

    // ---- vertex loop with row prefetch ----
    const int stride = gridDim.x * 4;
    int v = blockIdx.x * 4 + wid;
    if (v >= NV) return;

    const unsigned char* wp = ws + (size_t)v * 512 + (c << 5) + ((g & 1) << 4);
    const size_t wstep = (size_t)stride * 512;
    float* ob = out + (size_t)v * 144;
    const size_t ostep = (size_t)stride * 144;

    bf16x8 bin = *(const bf16x8*)(wp);

    for (; v < NV; v += stride) {
        const unsigned char* wpn = (v + stride < NV) ? (wp + wstep) : wp;
        bf16x8 nb = *(const bf16x8*)(wpn);

        f32x4 A[4];
        unsigned int pkv[4][2];

        // ---- layer 0 (bias via k=9 slot; C = 0) ----
        #pragma unroll
        for (int t = 0; t < 4; ++t) {
            f32x4 z4 = {0.f, 0.f, 0.f, 0.f};
            A[t] = __builtin_amdgcn_mfma_f32_16x16x32_bf16(w0f[t], bin, z4, 0, 0, 0);
        }
        #pragma unroll
        for (int t = 0; t < 4; ++t) {
            pkv[t][0] = pk2(eluf(A[t][0]), eluf(A[t][1]));
            pkv[t][1] = pk2(eluf(A[t][2]), eluf(A[t][3]));
        }
        B2 h = d2b(pkv, c, g);

        // ---- layer 1 (C = b1) ----
        #pragma unroll
        for (int t = 0; t < 4; ++t) {
            bf16x8 wa = rdW(sW1, c, g, t, 0);
            bf16x8 wb = rdW(sW1, c, g, t, 1);
            f32x4 a = { b1v[4*t+0], b1v[4*t+1], b1v[4*t+2], b1v[4*t+3] };
            a = __builtin_amdgcn_mfma_f32_16x16x32_bf16(wa, h.b0, a, 0, 0, 0);
            a = __builtin_amdgcn_mfma_f32_16x16x32_bf16(wb, h.b1, a, 0, 0, 0);
            A[t] = a;
        }
        #pragma unroll
        for (int t = 0; t < 4; ++t) {
            pkv[t][0] = pk2(eluf(A[t][0]), eluf(A[t][1]));
            pkv[t][1] = pk2(eluf(A[t][2]), eluf(A[t][3]));
        }
        h = d2b(pkv, c, g);

        // ---- layer 2 (C = b2) ----
        #pragma unroll
        for (int t = 0; t < 4; ++t) {
            bf16x8 wa = rdW(sW2, c, g, t, 0);
            bf16x8 wb = rdW(sW2, c, g, t, 1);
            f32x4 a = { b2v[4*t+0], b2v[4*t+1], b2v[4*t+2], b2v[4*t+3] };
            a = __builtin_amdgcn_mfma_f32_16x16x32_bf16(wa, h.b0, a, 0, 0, 0);
            a = __builtin_amdgcn_mfma_f32_16x16x32_bf16(wb, h.b1, a, 0, 0, 0);
            A[t] = a;
        }
        #pragma unroll
        for (int t = 0; t < 4; ++t) {
            pkv[t][0] = pk2(eluf(A[t][0]), eluf(A[t][1]));
            pkv[t][1] = pk2(eluf(A[t][2]), eluf(A[t][3]));
        }
        h = d2b(pkv, c, g);

        // ---- layer 3: 64 -> 9 (C = b3), stage to LDS ----
        {
            f32x4 a = { b3v[0], b3v[1], b3v[2], b3v[3] };
            a = __builtin_amdgcn_mfma_f32_16x16x32_bf16(w3f[0], h.b0, a, 0, 0, 0);
            a = __builtin_amdgcn_mfma_f32_16x16x32_bf16(w3f[1], h.b1, a, 0, 0, 0);
            if (g < 2) {
                fOut[c * 9 + 4 * g + 0] = eluf(a[0]);
                fOut[c * 9 + 4 * g + 1] = eluf(a[1]);
                fOut[c * 9 + 4 * g + 2] = eluf(a[2]);
                fOut[c * 9 + 4 * g + 3] = eluf(a[3]);
            } else if (g == 2) {
                fOut[c * 9 + 8] = eluf(a[0]);
            }
        }
        __asm__ volatile("s_waitcnt lgkmcnt(0)" ::: "memory");

        // ---- full-sector store: 36 lanes x contiguous float4 = 576B ----
        if (lane < 36) {
            float4 val = *(const float4*)(fOut + lane * 4);
            *(float4*)(ob + lane * 4) = val;
        }
        __asm__ volatile("s_waitcnt lgkmcnt(0)" ::: "memory");  // reads done before next writes

        bin = nb;
        wp = wpn;
        ob += ostep;
    }
}

// ---------------------------------------------------------------------------
// Fallback: round-1 fp32 fused kernel (only if ws too small)
// ---------------------------------------------------------------------------
__launch_bounds__(256, 2)
__global__ void fused_pca_mlp(const float* __restrict__ coords,
                              const float* __restrict__ distsq,
                              const float* __restrict__ feats,
                              const int*   __restrict__ nidx,
                              const float* __restrict__ W0, const float* __restrict__ b0,
                              const float* __restrict__ W1, const float* __restrict__ b1,
                              const float* __restrict__ W2, const float* __restrict__ b2,
                              const float* __restrict__ W3, const float* __restrict__ b3,
                              float* __restrict__ out)
{
    __shared__ __align__(16) float sW0t[64 * 9];
    __shared__ __align__(16) float sW1t[64 * 64];
    __shared__ __align__(16) float sW2t[64 * 64];
    __shared__ __align__(16) float sW3t[9 * 64];
    __shared__ float sB0[64], sB1[64], sB2[64], sB3[9];
    const int tid = threadIdx.x;
    for (int t = tid; t < 64 * 9; t += 256) { int j = t / 9, i = t - j * 9; sW0t[t] = W0[i * 64 + j]; }
    for (int t = tid; t < 64 * 64; t += 256) { int j = t >> 6, i = t & 63; sW1t[t] = W1[i * 64 + j]; }
    for (int t = tid; t < 64 * 64; t += 256) { int j = t >> 6, i = t & 63; sW2t[t] = W2[i * 64 + j]; }
    for (int t = tid; t < 9 * 64; t += 256) { int j = t >> 6, i = t & 63; sW3t[t] = W3[i * 9 + j]; }
    if (tid < 64) { sB0[tid] = b0[tid]; sB1[tid] = b1[tid]; sB2[tid] = b2[tid]; }
    if (tid < 9)  { sB3[tid] = b3[tid]; }
    __syncthreads();
    const int g = tid >> 4, f = tid & 15;
    const int v = blockIdx.x * 16 + g;
    if (v >= NV) return;
    const int* nix = nidx + (size_t)v * NK;
    const float* dsq = distsq + (size_t)v * NK;
    float s = 0.f, m0=0,m1=0,m2=0, q00=0,q01=0,q02=0,q11=0,q12=0,q22=0;
    #pragma unroll 4
    for (int k = 0; k < NK; ++k) {
        int idx = nix[k];
        float ew = __expf(-10.0f * dsq[k]);
        float w = feats[(size_t)idx * NF + f] * ew;
        float x = coords[(size_t)idx*3+0], y = coords[(size_t)idx*3+1], z = coords[(size_t)idx*3+2];
        s += w; m0 = fmaf(w,x,m0); m1 = fmaf(w,y,m1); m2 = fmaf(w,z,m2);
        float wx=w*x, wy=w*y, wz=w*z;
        q00=fmaf(wx,x,q00); q01=fmaf(wx,y,q01); q02=fmaf(wx,z,q02);
        q11=fmaf(wy,y,q11); q12=fmaf(wy,z,q12); q22=fmaf(wz,z,q22);
    }
    float inv = 1.0f/(s+EPS_W), mu0=m0*inv, mu1=m1*inv, mu2=m2*inv;
    float xr[9];
    xr[0]=fmaf(-mu0,mu0,q00*inv); xr[1]=fmaf(-mu0,mu1,q01*inv); xr[2]=fmaf(-mu0,mu2,q02*inv);
    xr[3]=xr[1]; xr[4]=fmaf(-mu1,mu1,q11*inv); xr[5]=fmaf(-mu1,mu2,q12*inv);
    xr[6]=xr[2]; xr[7]=xr[5]; xr[8]=fmaf(-mu2,mu2,q22*inv);
    float h[64], gg[64];
    #pragma unroll
    for (int j = 0; j < 64; ++j) {
        float aa = sB0[j]; const float* wr = sW0t + j * 9;
        #pragma unroll
        for (int i = 0; i < 9; ++i) aa = fmaf(xr[i], wr[i], aa);
        h[j] = eluf(aa);
    }
    #pragma unroll
    for (int j = 0; j < 64; ++j) {
        float aa = sB1[j]; const float4* wr = (const float4*)(sW1t + (j << 6));
        #pragma unroll
        for (int i4 = 0; i4 < 16; ++i4) { float4 wv = wr[i4];
            aa = fmaf(h[4*i4+0],wv.x,aa); aa = fmaf(h[4*i4+1],wv.y,aa);
            aa = fmaf(h[4*i4+2],wv.z,aa); aa = fmaf(h[4*i4+3],wv.w,aa); }
        gg[j] = eluf(aa);
    }
    #pragma unroll
    for (int j = 0; j < 64; ++j) {
        float aa = sB2[j]; const float4* wr = (const float4*)(sW2t + (j << 6));
        #pragma unroll
        for (int i4 = 0; i4 < 16; ++i4) { float4 wv = wr[i4];
            aa = fmaf(gg[4*i4+0],wv.x,aa); aa = fmaf(gg[4*i4+1],wv.y,aa);
            aa = fmaf(gg[4*i4+2],wv.z,aa); aa = fmaf(gg[4*i4+3],wv.w,aa); }
        h[j] = eluf(aa);
    }
    float o[9];
    #pragma unroll
    for (int j = 0; j < 9; ++j) {
        float aa = sB3[j]; const float4* wr = (const float4*)(sW3t + (j << 6));
        #pragma unroll
        for (int i4 = 0; i4 < 16; ++i4) { float4 wv = wr[i4];
            aa = fmaf(h[4*i4+0],wv.x,aa); aa = fmaf(h[4*i4+1],wv.y,aa);
            aa = fmaf(h[4*i4+2],wv.z,aa); aa = fmaf(h[4*i4+3],wv.w,aa); }
        o[j] = eluf(aa);
    }
    float* op = out + ((size_t)v * NF + f) * 9;
    #pragma unroll
    for (int j = 0; j < 9; ++j) op[j] = o[j];
}

extern "C" void kernel_launch(void* const* d_in, const int* in_sizes, int n_in,
                              void* d_out, int out_size, void* d_ws, size_t ws_size,
                              hipStream_t stream) {
    (void)in_sizes; (void)n_in; (void)out_size;
    const float* coords = (const float*)d_in[0];
    const float* distsq = (const float*)d_in[1];
    const float* feats  = (const float*)d_in[2];
    const int*   nidx   = (const int*)d_in[3];
    const float* W0 = (const float*)d_in[4];
    const float* b0 = (const float*)d_in[5];
    const float* W1 = (const float*)d_in[6];
    const float* b1 = (const float*)d_in[7];
    const float* W2 = (const float*)d_in[8];
    const float* b2 = (const float*)d_in[9];
    const float* W3 = (const float*)d_in[10];
    const float* b3 = (const float*)d_in[11];
    float* out = (float*)d_out;

    if (ws_size >= WS_NEED) {
        unsigned char* ws = (unsigned char*)d_ws;
        hipLaunchKernelGGL(cov3_kernel, dim3(NV / 8), dim3(256), 0, stream,
                           coords, distsq, feats, nidx, ws);
        hipLaunchKernelGGL(mlp6_kernel, dim3(GRID_MLP), dim3(256), 0, stream,
                           ws, W0, b0, W1, b1, W2, b2, W3, b3, out);
    } else {
        hipLaunchKernelGGL(fused_pca_mlp, dim3(NV / 16), dim3(256), 0, stream,
                           coords, distsq, feats, nidx,
                           W0, b0, W1, b1, W2, b2, W3, b3, out);
    }
}

// Round 12
// 212.532 us; speedup vs baseline: 1.3872x; 1.0108x over previous
//
#include <hip/hip_runtime.h>
#include <hip/hip_bf16.h>
#include <math.h>

#define NV 100000
#define NK 64
#define NF 16
#define EPS_W 1e-4f
#define WS_NEED ((size_t)NV * 16 * 32)   // 51.2 MB bf16 rows
#define GRID_MLP 3125                    // 12500 waves x 8 vertices each
#define STRIDE_MLP 12500

typedef __attribute__((ext_vector_type(8))) short bf16x8;
typedef __attribute__((ext_vector_type(4))) float f32x4;

__device__ __forceinline__ unsigned short bfu(float x) {
    return __builtin_bit_cast(unsigned short, (__bf16)x);   // HW RNE cvt
}
__device__ __forceinline__ unsigned int pk2(float lo, float hi) {
    float2 t; t.x = lo; t.y = hi;
    __hip_bfloat162 r = __float22bfloat162_rn(t);           // v_cvt_pk_bf16_f32
    unsigned int u;
    __builtin_memcpy(&u, &r, 4);
    return u;
}
__device__ __forceinline__ float eluf(float x) {
    return x > 0.f ? x : __expf(x) - 1.f;
}

// ---------------------------------------------------------------------------
// Kernel A (cov3): split-K covariance (r11-verified, ~78us).
// ---------------------------------------------------------------------------
__launch_bounds__(256)
__global__ void cov3_kernel(const float* __restrict__ coords,
                            const float* __restrict__ distsq,
                            const float* __restrict__ feats,
                            const int*   __restrict__ nidx,
                            unsigned char* __restrict__ ws)
{
    __shared__ float sEW[8][64];
    __shared__ int   sIX[8][64];
    const int tid = threadIdx.x;
    const int vb  = blockIdx.x * 8;

    #pragma unroll
    for (int r = 0; r < 2; ++r) {
        int t  = tid + r * 256;
        int gv = t >> 6, k = t & 63;
        float d  = distsq[(size_t)(vb + gv) * NK + k];
        int   ix = nidx [(size_t)(vb + gv) * NK + k];
        sEW[gv][k] = __expf(-10.f * d);
        sIX[gv][k] = ix;
    }
    __syncthreads();

    const int lane = tid & 63;
    const int wid  = tid >> 6;
    const int f    = lane & 15;
    const int kh   = (lane >> 4) & 1;
    const int g2   = lane >> 5;
    const int gv   = wid * 2 + g2;
    const int v    = vb + gv;

    float s=0.f, m0=0.f,m1=0.f,m2=0.f;
    float q00=0.f,q01=0.f,q02=0.f,q11=0.f,q12=0.f,q22=0.f;

    #pragma unroll 8
    for (int i = 0; i < 32; ++i) {
        int   k   = kh * 32 + i;
        int   idx = sIX[gv][k];
        float ew  = sEW[gv][k];
        float w   = feats[(size_t)idx * NF + f] * ew;
        float x = coords[(size_t)idx*3+0];
        float y = coords[(size_t)idx*3+1];
        float z = coords[(size_t)idx*3+2];
        s += w;
        m0 = fmaf(w,x,m0); m1 = fmaf(w,y,m1); m2 = fmaf(w,z,m2);
        float wx=w*x, wy=w*y, wz=w*z;
        q00=fmaf(wx,x,q00); q01=fmaf(wx,y,q01); q02=fmaf(wx,z,q02);
        q11=fmaf(wy,y,q11); q12=fmaf(wy,z,q12); q22=fmaf(wz,z,q22);
    }
    s   += __shfl_xor(s,   16);
    m0  += __shfl_xor(m0,  16);
    m1  += __shfl_xor(m1,  16);
    m2  += __shfl_xor(m2,  16);
    q00 += __shfl_xor(q00, 16);
    q01 += __shfl_xor(q01, 16);
    q02 += __shfl_xor(q02, 16);
    q11 += __shfl_xor(q11, 16);
    q12 += __shfl_xor(q12, 16);
    q22 += __shfl_xor(q22, 16);

    if (kh == 0) {
        float inv = 1.f / (s + EPS_W);
        float mu0=m0*inv, mu1=m1*inv, mu2=m2*inv;
        float c00=fmaf(-mu0,mu0,q00*inv);
        float c01=fmaf(-mu0,mu1,q01*inv);
        float c02=fmaf(-mu0,mu2,q02*inv);
        float c11=fmaf(-mu1,mu1,q11*inv);
        float c12=fmaf(-mu1,mu2,q12*inv);
        float c22=fmaf(-mu2,mu2,q22*inv);

        uint4 lo, hi;
        lo.x = pk2(c00, c01);
        lo.y = pk2(c02, c01);
        lo.z = pk2(c11, c12);
        lo.w = pk2(c02, c12);
        hi.x = pk2(c22, 1.0f);
        hi.y = 0u; hi.z = 0u; hi.w = 0u;

        uint4* dst = (uint4*)(ws + ((size_t)v * 16 + f) * 32);
        dst[0] = lo;
        dst[1] = hi;
    }
}

// ---------------------------------------------------------------------------
// Kernel B (mlp7): depth-2 software pipeline across vertices.
// Per loop body: {L2,L3+store of vertex k} interleaved with {L0,L1 of k+1} —
// two independent chains per wave, so MFMA clusters co-issue with the other
// chain's ELU/VALU and each lgkmcnt covers double the queued work (T15+T5).
// D layout: col=lane&15, row=16t+4g+reg.  A/B: row/col=lane&15, k=8g+i (+32kc).
// ---------------------------------------------------------------------------
__device__ __forceinline__ bf16x8 rdfrag(const short* hb, int c, int g, int kc) {
    int boff = ((kc << 6) + (g << 4)) ^ ((c & 7) << 4);
    return *(const bf16x8*)(hb + c * 64 + (boff >> 1));
}
__device__ __forceinline__ void wrH(short* hb, int c, int g, int t,
                                    unsigned int p01, unsigned int p23) {
    int boff = ((t << 5) + (g << 3)) ^ ((c & 7) << 4);
    uint2 val; val.x = p01; val.y = p23;
    *(uint2*)(hb + c * 64 + (boff >> 1)) = val;
}
__device__ __forceinline__ bf16x8 rdW(const short* sw, int c, int g, int t, int kc) {
    int byte = (t << 11) + (c << 7) + (kc << 6) + (g << 4);
    byte ^= (c & 7) << 4;
    return *(const bf16x8*)((const char*)sw + byte);
}

__launch_bounds__(256, 3)
__global__ void mlp7_kernel(const unsigned char* __restrict__ ws,
                            const float* __restrict__ W0, const float* __restrict__ b0,
                            const float* __restrict__ W1, const float* __restrict__ b1,
                            const float* __restrict__ W2, const float* __restrict__ b2,
                            const float* __restrict__ W3, const float* __restrict__ b3,
                            float* __restrict__ out)
{
    __shared__ __align__(16) short sW1[4096];        // 8 KB swizzled W1^T
    __shared__ __align__(16) short sW2[4096];        // 8 KB swizzled W2^T
    __shared__ __align__(16) short hbuf[4][2][1024]; // 16 KB: [wave][P/Q chain]
    __shared__ __align__(16) float sOut[4][160];     // 2.5 KB epilogue staging

    const int tid  = threadIdx.x;
    const int wid  = tid >> 6;
    const int lane = tid & 63;
    const int c    = lane & 15;
    const int g    = lane >> 4;

    union U8 { short s[8]; bf16x8 v; };

    // ---- stage W1,W2 into swizzled LDS ----
    #pragma unroll
    for (int r = 0; r < 2; ++r) {
        int t = tid + r * 256;
        int j = t & 63, o = t >> 6;
        U8 u1, u2;
        #pragma unroll
        for (int i = 0; i < 8; ++i) {
            u1.s[i] = (short)bfu(W1[(8 * o + i) * 64 + j]);
            u2.s[i] = (short)bfu(W2[(8 * o + i) * 64 + j]);
        }
        int byte = ((j << 7) + (o << 4)) ^ ((j & 7) << 4);
        *(bf16x8*)((char*)sW1 + byte) = u1.v;
        *(bf16x8*)((char*)sW2 + byte) = u2.v;
    }
    __syncthreads();

    // ---- W0 / W3 fragments + biases in VGPRs ----
    bf16x8 w0f[4], w3f[2];
    #pragma unroll
    for (int t = 0; t < 4; ++t) {
        U8 u;
        #pragma unroll
        for (int i = 0; i < 8; ++i) {
            int k = 8 * g + i;
            float val = 0.f;
            if (k < 9)       val = W0[k * 64 + 16 * t + c];
            else if (k == 9) val = b0[16 * t + c];       // bias via dim-9 = 1.0
            u.s[i] = (short)bfu(val);
        }
        w0f[t] = u.v;
    }
    #pragma unroll
    for (int kc = 0; kc < 2; ++kc) {
        U8 u;
        #pragma unroll
        for (int i = 0; i < 8; ++i) {
            int k = 32 * kc + 8 * g + i;
            u.s[i] = (short)bfu(c < 9 ? W3[k * 9 + c] : 0.f);
        }
        w3f[kc] = u.v;
    }
    float b1v[16], b2v[16], b3v[4];
    #pragma unroll
    for (int t = 0; t < 4; ++t)
        #pragma unroll
        for (int r = 0; r < 4; ++r) {
            b1v[4 * t + r] = b1[16 * t + 4 * g + r];
            b2v[4 * t + r] = b2[16 * t + 4 * g + r];
        }
    #pragma unroll
    for (int r = 0; r < 4; ++r)
        b3v[r] = (4 * g + r < 9) ? b3[4 * g + r] : 0.f;

    short* hbP = &hbuf[wid][0][0];
    short* hbQ = &hbuf[wid][1][0];
    float* fOut = &sOut[wid][0];

    const int v0 = blockIdx.x * 4 + wid;          // in [0, 12500)
    const unsigned char* base = ws + (c << 5) + ((g & 1) << 4);
    float* ob = out + (size_t)v0 * 144;
    const size_t ostep = (size_t)STRIDE_MLP * 144;

    bf16x8 hP0, hP1;

    // ---- prologue: L0+L1 of vertex v0 -> hP ----
    {
        bf16x8 bin = *(const bf16x8*)(base + (size_t)v0 * 512);
        f32x4 A[4];
        #pragma unroll
        for (int t = 0; t < 4; ++t) {
            f32x4 z4 = {0.f, 0.f, 0.f, 0.f};
            A[t] = __builtin_amdgcn_mfma_f32_16x16x32_bf16(w0f[t], bin, z4, 0, 0, 0);
        }
        #pragma unroll
        for (int t = 0; t < 4; ++t)
            wrH(hbQ, c, g, t, pk2(eluf(A[t][0]), eluf(A[t][1])),
                              pk2(eluf(A[t][2]), eluf(A[t][3])));
        __asm__ volatile("s_waitcnt lgkmcnt(0)" ::: "memory");
        bf16x8 h0 = rdfrag(hbQ, c, g, 0), h1 = rdfrag(hbQ, c, g, 1);
        #pragma unroll
        for (int t = 0; t < 4; ++t) {
            bf16x8 wa = rdW(sW1, c, g, t, 0);
            bf16x8 wb = rdW(sW1, c, g, t, 1);
            f32x4 a = { b1v[4*t+0], b1v[4*t+1], b1v[4*t+2], b1v[4*t+3] };
            a = __builtin_amdgcn_mfma_f32_16x16x32_bf16(wa, h0, a, 0, 0, 0);
            a = __builtin_amdgcn_mfma_f32_16x16x32_bf16(wb, h1, a, 0, 0, 0);
            A[t] = a;
        }
        #pragma unroll
        for (int t = 0; t < 4; ++t)
            wrH(hbQ, c, g, t, pk2(eluf(A[t][0]), eluf(A[t][1])),
                              pk2(eluf(A[t][2]), eluf(A[t][3])));
        __asm__ volatile("s_waitcnt lgkmcnt(0)" ::: "memory");
        hP0 = rdfrag(hbQ, c, g, 0);
        hP1 = rdfrag(hbQ, c, g, 1);
    }

    bf16x8 binQ = *(const bf16x8*)(base + (size_t)(v0 + STRIDE_MLP) * 512);

    // ---- steady state: k = 0..6 ----
    #pragma unroll 1
    for (int k = 0; k < 7; ++k) {
        int vpre = v0 + (k + 2 <= 7 ? (k + 2) : 7) * STRIDE_MLP;
        bf16x8 binR = *(const bf16x8*)(base + (size_t)vpre * 512);

        f32x4 AP[4], AQ[4];
        __builtin_amdgcn_s_setprio(1);
        // L2(vertex k) — chain P
        #pragma unroll
        for (int t = 0; t < 4; ++t) {
            bf16x8 wa = rdW(sW2, c, g, t, 0);
            bf16x8 wb = rdW(sW2, c, g, t, 1);
            f32x4 a = { b2v[4*t+0], b2v[4*t+1], b2v[4*t+2], b2v[4*t+3] };
            a = __builtin_amdgcn_mfma_f32_16x16x32_bf16(wa, hP0, a, 0, 0, 0);
            a = __builtin_amdgcn_mfma_f32_16x16x32_bf16(wb, hP1, a, 0, 0, 0);
            AP[t] = a;
        }
        // L0(vertex k+1) — chain Q
        #pragma unroll
        for (int t = 0; t < 4; ++t) {
            f32x4 z4 = {0.f, 0.f, 0.f, 0.f};
            AQ[t] = __builtin_amdgcn_mfma_f32_16x16x32_bf16(w0f[t], binQ, z4, 0, 0, 0);
        }
        __builtin_amdgcn_s_setprio(0);
        #pragma unroll
        for (int t = 0; t < 4; ++t) {
            wrH(hbP, c, g, t, pk2(eluf(AP[t][0]), eluf(AP[t][1])),
                              pk2(eluf(AP[t][2]), eluf(AP[t][3])));
            wrH(hbQ, c, g, t, pk2(eluf(AQ[t][0]), eluf(AQ[t][1])),
                              pk2(eluf(AQ[t][2]), eluf(AQ[t][3])));
        }
        __asm__ volatile("s_waitcnt lgkmcnt(0)" ::: "memory");

        bf16x8 hp0 = rdfrag(hbP, c, g, 0), hp1 = rdfrag(hbP, c, g, 1);
        bf16x8 hq0 = rdfrag(hbQ, c, g, 0), hq1 = rdfrag(hbQ, c, g, 1);
        __builtin_amdgcn_s_setprio(1);
        // L3(vertex k) — chain P
        f32x4 aP = { b3v[0], b3v[1], b3v[2], b3v[3] };
        aP = __builtin_amdgcn_mfma_f32_16x16x32_bf16(w3f[0], hp0, aP, 0, 0, 0);
        aP = __builtin_amdgcn_mfma_f32_16x16x32_bf16(w3f[1], hp1, aP, 0, 0, 0);
        // L1(vertex k+1) — chain Q
        #pragma unroll
        for (int t = 0; t < 4; ++t) {
            bf16x8 wa = rdW(sW1, c, g, t, 0);
            bf16x8 wb = rdW(sW1, c, g, t, 1);
            f32x4 a = { b1v[4*t+0], b1v[4*t+1], b1v[4*t+2], b1v[4*t+3] };
            a = __builtin_amdgcn_mfma_f32_16x16x32_bf16(wa, hq0, a, 0, 0, 0);
            a = __builtin_amdgcn_mfma_f32_16x16x32_bf16(wb, hq1, a, 0, 0, 0);
            AQ[t] = a;
        }
        __builtin_amdgcn_s_setprio(0);
        // stage P output + Q ELU/writes
        if (g < 2) {
            fOut[c * 9 + 4 * g + 0] = eluf(aP[0]);
            fOut[c * 9 + 4 * g + 1] = eluf(aP[1]);
            fOut[c * 9 + 4 * g + 2] = eluf(aP[2]);
            fOut[c * 9 + 4 * g + 3] = eluf(aP[3]);
        } else if (g == 2) {
            fOut[c * 9 + 8] = eluf(aP[0]);
        }
        #pragma unroll
        for (int t = 0; t < 4; ++t)
            wrH(hbQ, c, g, t, pk2(eluf(AQ[t][0]), eluf(AQ[t][1])),
                              pk2(eluf(AQ[t][2]), eluf(AQ[t][3])));
        __asm__ volatile("s_waitcnt lgkmcnt(0)" ::: "memory");

        // full-sector store of vertex k
        if (lane < 36) {
            float4 val = *(const float4*)(fOut + lane * 4);
            *(float4*)(ob + lane * 4) = val;
        }
        // rotate: B-frag for L2 of vertex k+1
        hP0 = rdfrag(hbQ, c, g, 0);
        hP1 = rdfrag(hbQ, c, g, 1);
        __asm__ volatile("s_waitcnt lgkmcnt(0)" ::: "memory");

        binQ = binR;
        ob += ostep;
    }

    // ---- epilogue: L2+L3+store of vertex 7 ----
    {
        f32x4 AP[4];
        #pragma unroll
        for (int t = 0; t < 4; ++t) {
            bf16x8 wa = rdW(sW2, c, g, t, 0);
            bf16x8 wb = rdW(sW2, c, g, t, 1);
            f32x4 a = { b2v[4*t+0], b2v[4*t+1], b2v[4*t+2], b2v[4*t+3] };
            a = __builtin_amdgcn_mfma_f32_16x16x32_bf16(wa, hP0, a, 0, 0, 0);
            a = __builtin_amdgcn_mfma_f32_16x16x32_bf16(wb, hP1, a, 0, 0, 0);
            AP[t] = a;
        }
        #pragma unroll
        for (int t = 0; t < 4; ++t)
            wrH(hbP, c, g, t, pk2(eluf(AP[t][0]), eluf(AP[t][1])),
                              pk2(eluf(AP[t][2]), eluf(AP[t][3])));
        __asm__ volatile("s_waitcnt lgkmcnt(0)" ::: "memory");
        bf16x8 hp0 = rdfrag(hbP, c, g, 0), hp1 = rdfrag(hbP, c, g, 1);
        f32x4 aP = { b3v[0], b3v[1], b3v[2], b3v[3] };
        aP = __builtin_amdgcn_mfma_f32_16x16x32_bf16(w3f[0], hp0, aP, 0, 0, 0);
        aP = __builtin_amdgcn_mfma_f32_16x16x32_bf16(w3f[1], hp1, aP, 0, 0, 0);
        if (g < 2) {
            fOut[c * 9 + 4 * g + 0] = eluf(aP[0]);
            fOut[c * 9 + 4 * g + 1] = eluf(aP[1]);
            fOut[c * 9 + 4 * g + 2] = eluf(aP[2]);
            fOut[c * 9 + 4 * g + 3] = eluf(aP[3]);
        } else if (g == 2) {
            fOut[c * 9 + 8] = eluf(aP[0]);
        }
        __asm__ volatile("s_waitcnt lgkmcnt(0)" ::: "memory");
        if (lane < 36) {
            float4 val = *(const float4*)(fOut + lane * 4);
            *(float4*)(ob + lane * 4) = val;
        }
    }
}

// ---------------------------------------------------------------------------
// Fallback: round-1 fp32 fused kernel (only if ws too small)
// ---------------------------------------------------------------------------
__launch_bounds__(256, 2)
__global__ void fused_pca_mlp(const float* __restrict__ coords,
                              const float* __restrict__ distsq,
                              const float* __restrict__ feats,
                              const int*   __restrict__ nidx,
                              const float* __restrict__ W0, const float* __restrict__ b0,
                              const float* __restrict__ W1, const float* __restrict__ b1,
                              const float* __restrict__ W2, const float* __restrict__ b2,
                              const float* __restrict__ W3, const float* __restrict__ b3,
                              float* __restrict__ out)
{
    __shared__ __align__(16) float sW0t[64 * 9];
    __shared__ __align__(16) float sW1t[64 * 64];
    __shared__ __align__(16) float sW2t[64 * 64];
    __shared__ __align__(16) float sW3t[9 * 64];
    __shared__ float sB0[64], sB1[64], sB2[64], sB3[9];
    const int tid = threadIdx.x;
    for (int t = tid; t < 64 * 9; t += 256) { int j = t / 9, i = t - j * 9; sW0t[t] = W0[i * 64 + j]; }
    for (int t = tid; t < 64 * 64; t += 256) { int j = t >> 6, i = t & 63; sW1t[t] = W1[i * 64 + j]; }
    for (int t = tid; t < 64 * 64; t += 256) { int j = t >> 6, i = t & 63; sW2t[t] = W2[i * 64 + j]; }
    for (int t = tid; t < 9 * 64; t += 256) { int j = t >> 6, i = t & 63; sW3t[t] = W3[i * 9 + j]; }
    if (tid < 64) { sB0[tid] = b0[tid]; sB1[tid] = b1[tid]; sB2[tid] = b2[tid]; }
    if (tid < 9)  { sB3[tid] = b3[tid]; }
    __syncthreads();
    const int g = tid >> 4, f = tid & 15;
    const int v = blockIdx.x * 16 + g;
    if (v >= NV) return;
    const int* nix = nidx + (size_t)v * NK;
    const float* dsq = distsq + (size_t)v * NK;
    float s = 0.f, m0=0,m1=0,m2=0, q00=0,q01=0,q02=0,q11=0,q12=0,q22=0;
    #pragma unroll 4
    for (int k = 0; k < NK; ++k) {
        int idx = nix[k];
        float ew = __expf(-10.0f * dsq[k]);
        float w = feats[(size_t)idx * NF + f] * ew;
        float x = coords[(size_t)idx*3+0], y = coords[(size_t)idx*3+1], z = coords[(size_t)idx*3+2];
        s += w; m0 = fmaf(w,x,m0); m1 = fmaf(w,y,m1); m2 = fmaf(w,z,m2);
        float wx=w*x, wy=w*y, wz=w*z;
        q00=fmaf(wx,x,q00); q01=fmaf(wx,y,q01); q02=fmaf(wx,z,q02);
        q11=fmaf(wy,y,q11); q12=fmaf(wy,z,q12); q22=fmaf(wz,z,q22);
    }
    float inv = 1.0f/(s+EPS_W), mu0=m0*inv, mu1=m1*inv, mu2=m2*inv;
    float xr[9];
    xr[0]=fmaf(-mu0,mu0,q00*inv); xr[1]=fmaf(-mu0,mu1,q01*inv); xr[2]=fmaf(-mu0,mu2,q02*inv);
    xr[3]=xr[1]; xr[4]=fmaf(-mu1,mu1,q11*inv); xr[5]=fmaf(-mu1,mu2,q12*inv);
    xr[6]=xr[2]; xr[7]=xr[5]; xr[8]=fmaf(-mu2,mu2,q22*inv);
    float h[64], gg[64];
    #pragma unroll
    for (int j = 0; j < 64; ++j) {
        float aa = sB0[j]; const float* wr = sW0t + j * 9;
        #pragma unroll
        for (int i = 0; i < 9; ++i) aa = fmaf(xr[i], wr[i], aa);
        h[j] = eluf(aa);
    }
    #pragma unroll
    for (int j = 0; j < 64; ++j) {
        float aa = sB1[j]; const float4* wr = (const float4*)(sW1t + (j << 6));
        #pragma unroll
        for (int i4 = 0; i4 < 16; ++i4) { float4 wv = wr[i4];
            aa = fmaf(h[4*i4+0],wv.x,aa); aa = fmaf(h[4*i4+1],wv.y,aa);
            aa = fmaf(h[4*i4+2],wv.z,aa); aa = fmaf(h[4*i4+3],wv.w,aa); }
        gg[j] = eluf(aa);
    }
    #pragma unroll
    for (int j = 0; j < 64; ++j) {
        float aa = sB2[j]; const float4* wr = (const float4*)(sW2t + (j << 6));
        #pragma unroll
        for (int i4 = 0; i4 < 16; ++i4) { float4 wv = wr[i4];
            aa = fmaf(gg[4*i4+0],wv.x,aa); aa = fmaf(gg[4*i4+1],wv.y,aa);
            aa = fmaf(gg[4*i4+2],wv.z,aa); aa = fmaf(gg[4*i4+3],wv.w,aa); }
        h[j] = eluf(aa);
    }
    float o[9];
    #pragma unroll
    for (int j = 0; j < 9; ++j) {
        float aa = sB3[j]; const float4* wr = (const float4*)(sW3t + (j << 6));
        #pragma unroll
        for (int i4 = 0; i4 < 16; ++i4) { float4 wv = wr[i4];
            aa = fmaf(h[4*i4+0],wv.x,aa); aa = fmaf(h[4*i4+1],wv.y,aa);
            aa = fmaf(h[4*i4+2],wv.z,aa); aa = fmaf(h[4*i4+3],wv.w,aa); }
        o[j] = eluf(aa);
    }
    float* op = out + ((size_t)v * NF + f) * 9;
    #pragma unroll
    for (int j = 0; j < 9; ++j) op[j] = o[j];
}

extern "C" void kernel_launch(void* const* d_in, const int* in_sizes, int n_in,
                              void* d_out, int out_size, void* d_ws, size_t ws_size,
                              hipStream_t stream) {
    (void)in_sizes; (void)n_in; (void)out_size;
    const float* coords = (const float*)d_in[0];
    const float* distsq = (const float*)d_in[1];
    const float* feats  = (const float*)d_in[2];
    const int*   nidx   = (const int*)d_in[3];
    const float* W0 = (const float*)d_in[4];
    const float* b0 = (const float*)d_in[5];
    const float* W1 = (const float*)d_in[6];
    const float* b1 = (const float*)d_in[7];
    const float* W2 = (const float*)d_in[8];
    const float* b2 = (const float*)d_in[9];
    const float* W3 = (const float*)d_in[10];
    const float* b3 = (const float*)d_in[11];
    float* out = (float*)d_out;

    if (ws_size >= WS_NEED) {
        unsigned char* ws = (unsigned char*)d_ws;
        hipLaunchKernelGGL(cov3_kernel, dim3(NV / 8), dim3(256), 0, stream,
                           coords, distsq, feats, nidx, ws);
        hipLaunchKernelGGL(mlp7_kernel, dim3(GRID_MLP), dim3(256), 0, stream,
                           ws, W0, b0, W1, b1, W2, b2, W3, b3, out);
    } else {
        hipLaunchKernelGGL(fused_pca_mlp, dim3(NV / 16), dim3(256), 0, stream,
                           coords, distsq, feats, nidx,
                           W0, b0, W1, b1, W2, b2, W3, b3, out);
    }
}